// Round 4
// baseline (925.636 us; speedup 1.0000x reference)
//
#include <hip/hip_runtime.h>

typedef __attribute__((ext_vector_type(8))) short bf16x8;
typedef __attribute__((ext_vector_type(4))) float f32x4;
typedef __attribute__((ext_vector_type(4))) float f4v;

__device__ __forceinline__ unsigned short f2bf(float f){
  unsigned u = __builtin_bit_cast(unsigned, f);
  u += 0x7FFFu + ((u >> 16) & 1u);
  return (unsigned short)(u >> 16);
}
__device__ __forceinline__ float bf2f(unsigned short b){
  unsigned u = ((unsigned)b) << 16;
  return __builtin_bit_cast(float, u);
}
__device__ __forceinline__ float sigmoidf_(float x){ return 1.f/(1.f + __expf(-x)); }
__device__ __forceinline__ float tanhf_(float x){
  float a = fabsf(x);
  float t = __expf(-2.f*a);
  float r = (1.f - t)/(1.f + t);
  return copysignf(r, x);
}

struct WF { bf16x8 hi, lo; };

__device__ __forceinline__ void mmsplit(bf16x8 ah, bf16x8 al, const WF& B,
                                        f32x4& Dh, f32x4& Dl){
  Dh = __builtin_amdgcn_mfma_f32_16x16x32_bf16(ah, B.hi, Dh, 0, 0, 0);
  Dl = __builtin_amdgcn_mfma_f32_16x16x32_bf16(al, B.hi, Dl, 0, 0, 0);
  Dl = __builtin_amdgcn_mfma_f32_16x16x32_bf16(ah, B.lo, Dl, 0, 0, 0);
}

__device__ __forceinline__ WF load_wf(const float* W, int ldk, int row, int k0, int kmax){
  WF f;
  #pragma unroll
  for (int j = 0; j < 8; j++){
    int k = k0 + j;
    float v = (k < kmax) ? W[row*ldk + k] : 0.f;
    unsigned short hb = f2bf(v);
    f.hi[j] = (short)hb;
    f.lo[j] = (short)f2bf(v - bf2f(hb));
  }
  return f;
}

// ---------------- GRU: 2 layers fused, 16 nodes per WG, 1 barrier/step ----------------
__global__ __launch_bounds__(256, 1)
void gru_kernel(const float* __restrict__ x,
                const float* __restrict__ Wih0, const float* __restrict__ Whh0,
                const float* __restrict__ bih0, const float* __restrict__ bhh0,
                const float* __restrict__ Wih1, const float* __restrict__ Whh1,
                const float* __restrict__ bih1, const float* __restrict__ bhh1,
                float* __restrict__ hfin){
  __shared__ unsigned short xp_hi[16][60][8];
  __shared__ unsigned short xp_lo[16][60][8];
  __shared__ unsigned short h0hi[2][16][72], h0lo[2][16][72];
  __shared__ unsigned short h1hi[2][16][72], h1lo[2][16][72];

  const int tid  = threadIdx.x;
  const int lane = tid & 63;
  const int w    = tid >> 6;
  const int c    = lane & 15;
  const int q    = lane >> 4;
  const int d    = w*16 + c;
  const int nbase = blockIdx.x * 16;

  for (int v = tid; v < 16*360; v += 256){
    int n = v / 360, rem = v % 360;
    int dd = rem / 60, tt = rem % 60;
    float f = x[(size_t)(nbase + n)*360 + rem];
    unsigned short hb = f2bf(f);
    xp_hi[n][tt][dd] = hb;
    xp_lo[n][tt][dd] = f2bf(f - bf2f(hb));
  }
  for (int v = tid; v < 16*60*2; v += 256){
    int n = v / 120, rem = v % 120;
    int tt = rem >> 1, dd = 6 + (rem & 1);
    xp_hi[n][tt][dd] = 0; xp_lo[n][tt][dd] = 0;
  }
  for (int v = tid; v < 2*16*72; v += 256){
    ((unsigned short*)h0hi)[v] = 0; ((unsigned short*)h0lo)[v] = 0;
    ((unsigned short*)h1hi)[v] = 0; ((unsigned short*)h1lo)[v] = 0;
  }

  const float bi0r = bih0[d], bi0z = bih0[64+d], bi0n = bih0[128+d];
  const float bh0r = bhh0[d], bh0z = bhh0[64+d], bh0n = bhh0[128+d];
  const float bi1r = bih1[d], bi1z = bih1[64+d], bi1n = bih1[128+d];
  const float bh1r = bhh1[d], bh1z = bhh1[64+d], bh1n = bhh1[128+d];

  WF Bih0[3];
  WF Bhh0[3][2], Bih1[3][2], Bhh1[3][2];
  #pragma unroll
  for (int g = 0; g < 3; g++){
    int row = g*64 + d;
    Bih0[g] = load_wf(Wih0, 6, row, q*8, 6);
    #pragma unroll
    for (int kt = 0; kt < 2; kt++){
      Bhh0[g][kt] = load_wf(Whh0, 64, row, kt*32 + q*8, 64);
      Bih1[g][kt] = load_wf(Wih1, 64, row, kt*32 + q*8, 64);
      Bhh1[g][kt] = load_wf(Whh1, 64, row, kt*32 + q*8, 64);
    }
  }

  float h0old[4] = {0,0,0,0}, h1old[4] = {0,0,0,0};

  __syncthreads();

  #pragma unroll 1
  for (int t = 0; t < 60; t++){
    const int p  = t & 1;
    const int qb = p ^ 1;

    bf16x8 a_h0h[2], a_h0l[2];
    #pragma unroll
    for (int kt = 0; kt < 2; kt++){
      a_h0h[kt] = *(const bf16x8*)&h0hi[p][c][kt*32 + q*8];
      a_h0l[kt] = *(const bf16x8*)&h0lo[p][c][kt*32 + q*8];
    }
    bf16x8 a_xh = {}, a_xl = {};
    if (q == 0){
      a_xh = *(const bf16x8*)&xp_hi[c][t][0];
      a_xl = *(const bf16x8*)&xp_lo[c][t][0];
    }

    f32x4 RH = {0,0,0,0}, RL = {0,0,0,0};
    f32x4 ZH = {0,0,0,0}, ZL = {0,0,0,0};
    f32x4 NIH = {0,0,0,0}, NIL = {0,0,0,0};
    f32x4 NHH = {0,0,0,0}, NHL = {0,0,0,0};
    mmsplit(a_xh, a_xl, Bih0[0], RH, RL);
    mmsplit(a_xh, a_xl, Bih0[1], ZH, ZL);
    mmsplit(a_xh, a_xl, Bih0[2], NIH, NIL);
    #pragma unroll
    for (int kt = 0; kt < 2; kt++){
      mmsplit(a_h0h[kt], a_h0l[kt], Bhh0[0][kt], RH, RL);
      mmsplit(a_h0h[kt], a_h0l[kt], Bhh0[1][kt], ZH, ZL);
      mmsplit(a_h0h[kt], a_h0l[kt], Bhh0[2][kt], NHH, NHL);
    }
    #pragma unroll
    for (int rI = 0; rI < 4; rI++){
      float rv = sigmoidf_(RH[rI] + RL[rI] + bi0r + bh0r);
      float zv = sigmoidf_(ZH[rI] + ZL[rI] + bi0z + bh0z);
      float nv = tanhf_(NIH[rI] + NIL[rI] + bi0n + rv*(NHH[rI] + NHL[rI] + bh0n));
      float hnew = (1.f - zv)*nv + zv*h0old[rI];
      h0old[rI] = hnew;
      unsigned short hb = f2bf(hnew);
      int node = q*4 + rI;
      h0hi[qb][node][d] = hb;
      h0lo[qb][node][d] = f2bf(hnew - bf2f(hb));
    }
    __syncthreads();

    bf16x8 a_yh[2], a_yl[2], a_h1h[2], a_h1l[2];
    #pragma unroll
    for (int kt = 0; kt < 2; kt++){
      a_yh[kt]  = *(const bf16x8*)&h0hi[qb][c][kt*32 + q*8];
      a_yl[kt]  = *(const bf16x8*)&h0lo[qb][c][kt*32 + q*8];
      a_h1h[kt] = *(const bf16x8*)&h1hi[p][c][kt*32 + q*8];
      a_h1l[kt] = *(const bf16x8*)&h1lo[p][c][kt*32 + q*8];
    }
    f32x4 EH = {0,0,0,0}, EL = {0,0,0,0};
    f32x4 FH = {0,0,0,0}, FL = {0,0,0,0};
    f32x4 GIH = {0,0,0,0}, GIL = {0,0,0,0};
    f32x4 GHH = {0,0,0,0}, GHL = {0,0,0,0};
    #pragma unroll
    for (int kt = 0; kt < 2; kt++){
      mmsplit(a_yh[kt], a_yl[kt], Bih1[0][kt], EH, EL);
      mmsplit(a_yh[kt], a_yl[kt], Bih1[1][kt], FH, FL);
      mmsplit(a_yh[kt], a_yl[kt], Bih1[2][kt], GIH, GIL);
      mmsplit(a_h1h[kt], a_h1l[kt], Bhh1[0][kt], EH, EL);
      mmsplit(a_h1h[kt], a_h1l[kt], Bhh1[1][kt], FH, FL);
      mmsplit(a_h1h[kt], a_h1l[kt], Bhh1[2][kt], GHH, GHL);
    }
    #pragma unroll
    for (int rI = 0; rI < 4; rI++){
      float rv = sigmoidf_(EH[rI] + EL[rI] + bi1r + bh1r);
      float zv = sigmoidf_(FH[rI] + FL[rI] + bi1z + bh1z);
      float nv = tanhf_(GIH[rI] + GIL[rI] + bi1n + rv*(GHH[rI] + GHL[rI] + bh1n));
      float hnew = (1.f - zv)*nv + zv*h1old[rI];
      h1old[rI] = hnew;
      unsigned short hb = f2bf(hnew);
      int node = q*4 + rI;
      h1hi[qb][node][d] = hb;
      h1lo[qb][node][d] = f2bf(hnew - bf2f(hb));
    }
  }

  #pragma unroll
  for (int rI = 0; rI < 4; rI++){
    int node = nbase + q*4 + rI;
    hfin[(size_t)node*64 + d] = h1old[rI];
  }
}

// ---------------- a,c per head: a=h@W[:64], c=h@W[64:] ----------------
__global__ void ac_kernel(const float* __restrict__ hfin,
                          const float* __restrict__ W0h, const float* __restrict__ W1h,
                          const float* __restrict__ W2h, float* __restrict__ ac){
  int lane = threadIdx.x & 63;
  int node = blockIdx.x*4 + (threadIdx.x >> 6);
  float hv = hfin[(size_t)node*64 + lane];
  const float* Ws[3] = {W0h, W1h, W2h};
  #pragma unroll
  for (int h = 0; h < 3; h++){
    float pa = hv * Ws[h][lane];
    float pc = hv * Ws[h][64 + lane];
    #pragma unroll
    for (int m = 32; m >= 1; m >>= 1){
      pa += __shfl_xor(pa, m, 64);
      pc += __shfl_xor(pc, m, 64);
    }
    if (lane == 0){
      ac[(size_t)(2*h)*4000 + node]   = pa;
      ac[(size_t)(2*h+1)*4000 + node] = pc;
    }
  }
}

// -------- fused 3-head masked softmax + aggregation + fc; 4 rows/WG --------
// wave w owns row i0+w for streaming/softmax; weights stored m[j][4] for pass C.
__global__ __launch_bounds__(256, 2)
void attn4_kernel(const float* __restrict__ rel, const float* __restrict__ hfin,
                  const float* __restrict__ ac,
                  const float* __restrict__ b0p, const float* __restrict__ b1p,
                  const float* __restrict__ b2p,
                  const float* __restrict__ fcw, const float* __restrict__ fcb,
                  float* __restrict__ pred){
  __shared__ float m[4096][4];            // [j][row-in-block]
  __shared__ float aggred[4][4][64];      // [wave][row][dim]

  const int tid  = threadIdx.x;
  const int lane = tid & 63;
  const int w    = tid >> 6;
  const int i0   = blockIdx.x * 4;
  const int i    = i0 + w;                // this wave's row
  const float bh[3] = {b0p[0], b1p[0], b2p[0]};

  const float* c0 = ac + 1*4000;
  const float* c1 = ac + 3*4000;
  const float* c2 = ac + 5*4000;

  float ai[3];
  #pragma unroll
  for (int h = 0; h < 3; h++) ai[h] = ac[(size_t)(2*h)*4000 + i];

  const float* rowp = rel + (size_t)i*4000*8;
  float z[3] = {0.f, 0.f, 0.f};

  // Pass A: wave-private stream of row i, depth-2 prefetch (plain loads keep L3 hits)
  {
    int j0 = lane, j1 = lane + 64;
    f4v a0 = *(const f4v*)(rowp + (size_t)j0*8);
    f4v a1 = *(const f4v*)(rowp + (size_t)j0*8 + 4);
    f4v b0 = *(const f4v*)(rowp + (size_t)j1*8);
    f4v b1 = *(const f4v*)(rowp + (size_t)j1*8 + 4);
    for (int base = 0; base < 4000; base += 128){
      int cj0 = base + lane, cj1 = base + 64 + lane;
      int nj0 = cj0 + 128, nj1 = cj1 + 128;
      f4v na0, na1, nb0, nb1;
      if (nj0 < 4000){
        na0 = *(const f4v*)(rowp + (size_t)nj0*8);
        na1 = *(const f4v*)(rowp + (size_t)nj0*8 + 4);
      }
      if (nj1 < 4000){
        nb0 = *(const f4v*)(rowp + (size_t)nj1*8);
        nb1 = *(const f4v*)(rowp + (size_t)nj1*8 + 4);
      }
      if (cj0 < 4000){
        float mk = a0[0]+a0[1]+a0[2]+a0[3] + a1[0]+a1[1]+a1[2]+a1[3];
        m[cj0][w] = mk;
        float cv[3] = {c0[cj0], c1[cj0], c2[cj0]};
        #pragma unroll
        for (int h = 0; h < 3; h++){
          float s = ai[h] + cv[h] + bh[h];
          float wv = s > 0.f ? s : 0.01f*s;
          float val = (mk == 0.f) ? -1e6f : mk*wv;
          z[h] += __expf(val);
        }
      }
      if (cj1 < 4000){
        float mk = b0[0]+b0[1]+b0[2]+b0[3] + b1[0]+b1[1]+b1[2]+b1[3];
        m[cj1][w] = mk;
        float cv[3] = {c0[cj1], c1[cj1], c2[cj1]};
        #pragma unroll
        for (int h = 0; h < 3; h++){
          float s = ai[h] + cv[h] + bh[h];
          float wv = s > 0.f ? s : 0.01f*s;
          float val = (mk == 0.f) ? -1e6f : mk*wv;
          z[h] += __expf(val);
        }
      }
      a0 = na0; a1 = na1; b0 = nb0; b1 = nb1;
    }
  }
  // wave-local Z reduce (row fully owned by this wave)
  float iZ[3];
  #pragma unroll
  for (int h = 0; h < 3; h++){
    float v = z[h];
    #pragma unroll
    for (int mm = 32; mm >= 1; mm >>= 1) v += __shfl_xor(v, mm, 64);
    iZ[h] = 1.f/v;
  }

  // Pass B: wave rewrites its own column m[j][w] with the combined normalized weight
  for (int j = lane; j < 4000; j += 64){
    float mk = m[j][w];
    float cv[3] = {c0[j], c1[j], c2[j]};
    float ws = 0.f;
    #pragma unroll
    for (int h = 0; h < 3; h++){
      float s = ai[h] + cv[h] + bh[h];
      float wv = s > 0.f ? s : 0.01f*s;
      float val = (mk == 0.f) ? -1e6f : mk*wv;
      ws += __expf(val) * iZ[h];
    }
    m[j][w] = ws * (1.f/3.f);
  }
  __syncthreads();

  // Pass C: agg[r][d] = sum_j m[j][r] * h[j][d]
  // lane: jq = lane>>4 (j subgroup), d4 = lane&15 (float4 of dims). wave w: j in [w*1000,(w+1)*1000)
  const int jq = lane >> 4, d4 = lane & 15;
  const int jb = w * 1000;
  f4v acc[4] = {{0,0,0,0},{0,0,0,0},{0,0,0,0},{0,0,0,0}};
  #pragma unroll 2
  for (int jj = 0; jj < 1000; jj += 4){
    int j = jb + jj + jq;
    f4v wv = *(const f4v*)&m[j][0];
    f4v hv = *(const f4v*)&hfin[(size_t)j*64 + d4*4];
    #pragma unroll
    for (int r = 0; r < 4; r++)
      acc[r] += wv[r] * hv;
  }
  #pragma unroll
  for (int r = 0; r < 4; r++){
    #pragma unroll
    for (int e = 0; e < 4; e++){
      acc[r][e] += __shfl_xor(acc[r][e], 16, 64);
      acc[r][e] += __shfl_xor(acc[r][e], 32, 64);
    }
  }
  if (jq == 0){
    #pragma unroll
    for (int r = 0; r < 4; r++)
      *(f4v*)&aggred[w][r][d4*4] = acc[r];
  }
  __syncthreads();

  // epilogue: wave r reduces row i0+r
  {
    int r = w, dd = lane;
    float agg = aggred[0][r][dd] + aggred[1][r][dd] + aggred[2][r][dd] + aggred[3][r][dd];
    float term = hfin[(size_t)(i0+r)*64 + dd]*fcw[dd] + agg*fcw[64 + dd];
    #pragma unroll
    for (int mm = 32; mm >= 1; mm >>= 1) term += __shfl_xor(term, mm, 64);
    if (dd == 0) pred[i0 + r] = term + fcb[0];
  }
}

extern "C" void kernel_launch(void* const* d_in, const int* in_sizes, int n_in,
                              void* d_out, int out_size, void* d_ws, size_t ws_size,
                              hipStream_t stream) {
  const float* x    = (const float*)d_in[0];
  const float* rel  = (const float*)d_in[1];
  const float* Wih0 = (const float*)d_in[2];
  const float* Whh0 = (const float*)d_in[3];
  const float* bih0 = (const float*)d_in[4];
  const float* bhh0 = (const float*)d_in[5];
  const float* Wih1 = (const float*)d_in[6];
  const float* Whh1 = (const float*)d_in[7];
  const float* bih1 = (const float*)d_in[8];
  const float* bhh1 = (const float*)d_in[9];
  const float* W0   = (const float*)d_in[10];
  const float* b0   = (const float*)d_in[11];
  const float* W1   = (const float*)d_in[12];
  const float* b1   = (const float*)d_in[13];
  const float* W2   = (const float*)d_in[14];
  const float* b2   = (const float*)d_in[15];
  const float* fcw  = (const float*)d_in[16];
  const float* fcb  = (const float*)d_in[17];
  float* pred = (float*)d_out;
  float* hfin = (float*)d_ws;          // 4000*64 f32
  float* ac   = hfin + 4000*64;        // 6*4000 f32

  gru_kernel<<<dim3(250), dim3(256), 0, stream>>>(x, Wih0, Whh0, bih0, bhh0,
                                                  Wih1, Whh1, bih1, bhh1, hfin);
  ac_kernel<<<dim3(1000), dim3(256), 0, stream>>>(hfin, W0, W1, W2, ac);
  attn4_kernel<<<dim3(1000), dim3(256), 0, stream>>>(rel, hfin, ac, b0, b1, b2,
                                                     fcw, fcb, pred);
}